// Round 1
// baseline (437.194 us; speedup 1.0000x reference)
//
#include <hip/hip_runtime.h>
#include <math.h>

typedef float f4 __attribute__((ext_vector_type(4)));
typedef float f2 __attribute__((ext_vector_type(2)));

#define L_LEN 2048
#define C_DIM 96
#define N_DIM 16
#define P_DIM 38
#define R_DIM 6
#define G_DIM 12
#define B_DIM 4

// workspace layout (floats)
#define SZ_DELTA (B_DIM * G_DIM * C_DIM * L_LEN) // 9437184
#define SZ_BC (B_DIM * G_DIM * N_DIM * L_LEN)    // 1572864
#define SZ_U6 (B_DIM * 6 * C_DIM * L_LEN)        // 4718592

// ---------------- K1: cross-scan gather + projections ----------------
// thread = one (b,k,s,l). Computes xs value per c on the fly, projects to
// P=38 (acc in regs, weights via block-uniform scalar loads), writes
// delta (after dt-proj + bias + softplus), Bs, Cs, and u (k<2 only;
// k>=2 u is the l-reversal of k-2).
__global__ __launch_bounds__(256) void k1_proj(
    const float* __restrict__ x, const float* __restrict__ xpw,
    const float* __restrict__ dtw, const float* __restrict__ dtb,
    float* __restrict__ delta, float* __restrict__ Bsw,
    float* __restrict__ Csw, float* __restrict__ u6)
{
    int blk = blockIdx.x;
    int ltile = blk & 7;  // 8 tiles of 256 l's
    int bks = blk >> 3;   // 0..47
    int s = bks % 3;
    int k = (bks / 3) & 3;
    int b = bks / 12;
    int g = k * 3 + s;
    int l = ltile * 256 + (int)threadIdx.x;
    int lf = (k < 2) ? l : (L_LEN - 1 - l);
    int s2 = lf & 1;
    int hh, ww;
    if ((k & 1) == 0) { hh = lf >> 6; ww = (lf >> 1) & 31; }
    else              { ww = lf >> 6; hh = (lf >> 1) & 31; }
    int pix = hh * 32 + ww;

    const float* xb = x + (size_t)b * 2 * C_DIM * 1024 + pix;
    const float* wp = xpw + (size_t)g * P_DIM * C_DIM;

    float acc[P_DIM];
#pragma unroll
    for (int p = 0; p < P_DIM; ++p) acc[p] = 0.f;

    for (int c = 0; c < C_DIM; ++c) {
        float x0 = xb[(size_t)c * 1024];
        float x1 = xb[(size_t)(C_DIM + c) * 1024];
        float v;
        if (s == 2)      v = s2 ? x1 : x0;           // comm stream: x[s2]
        else if (s2)     v = s ? x1 : x0;            // s2==S-1: x[s1]
        else             v = s ? (x1 - x0) : (x0 - x1); // diff (incl diag fix)
        if (k < 2) u6[(((size_t)b * 6 + g) * C_DIM + c) * L_LEN + l] = v;
#pragma unroll
        for (int p = 0; p < P_DIM; ++p) acc[p] += v * wp[p * C_DIM + c];
    }

    size_t bg = (size_t)b * G_DIM + g;
    // dts(acc[0..5]) -> delta over all c, + bias, softplus
    const float* wd = dtw + (size_t)g * C_DIM * R_DIM;
    const float* bias = dtb + g * C_DIM;
    for (int c = 0; c < C_DIM; ++c) {
        float dsum = bias[c];
#pragma unroll
        for (int r = 0; r < R_DIM; ++r) dsum += acc[r] * wd[c * R_DIM + r];
        float sp = (dsum > 20.f) ? dsum : log1pf(__expf(dsum));
        delta[(bg * C_DIM + c) * L_LEN + l] = sp;
    }
#pragma unroll
    for (int n = 0; n < N_DIM; ++n) {
        Bsw[(bg * N_DIM + n) * L_LEN + l] = acc[6 + n];
        Csw[(bg * N_DIM + n) * L_LEN + l] = acc[22 + n];
    }
}

// ---------------- K2: selective scan ----------------
template <int CTRL>
__device__ __forceinline__ float dpp_sr(float v)
{
    int r = __builtin_amdgcn_update_dpp(0, __builtin_bit_cast(int, v), CTRL, 0xF, 0xF, true);
    return __builtin_bit_cast(float, r);
}

// block = 256 threads = 16 channels x 16 state-lanes. 6 blocks per (b,g).
__global__ __launch_bounds__(256) void k2_scan(
    const float* __restrict__ delta, const float* __restrict__ Bsw,
    const float* __restrict__ Csw, const float* __restrict__ u6,
    const float* __restrict__ A_logs, const float* __restrict__ Ds,
    float* __restrict__ yss)
{
    int blk = blockIdx.x; // (b*12+g)*6 + cblk
    int cblk = blk % 6;
    int bg = blk / 6;
    int g = bg % 12;
    int b = bg / 12;
    int n = threadIdx.x & 15;
    int c = cblk * 16 + (threadIdx.x >> 4);

    float a = -__expf(A_logs[(g * C_DIM + c) * N_DIM + n]);
    float dsc = Ds[g * C_DIM + c];
    const float* dptr = delta + ((size_t)bg * C_DIM + c) * L_LEN;
    const float* bptr = Bsw + ((size_t)bg * N_DIM + n) * L_LEN;
    const float* cptr = Csw + ((size_t)bg * N_DIM + n) * L_LEN;
    int gu = (g >= 6) ? (g - 6) : g;
    const float* uptr = u6 + (((size_t)b * 6 + gu) * C_DIM + c) * L_LEN;
    const bool rev = (g >= 6);
    float* yptr = yss + ((size_t)bg * C_DIM + c) * L_LEN;

    float h = 0.f;
    f4 d4 = *(const f4*)(dptr);
    f4 b4 = *(const f4*)(bptr);
    f4 c4 = *(const f4*)(cptr);
    f4 u4 = rev ? *(const f4*)(uptr + L_LEN - 4) : *(const f4*)(uptr);

    for (int l0 = 0; l0 < L_LEN; l0 += 4) {
        int ln = (l0 + 4 < L_LEN) ? (l0 + 4) : l0;
        f4 nd = *(const f4*)(dptr + ln);
        f4 nb = *(const f4*)(bptr + ln);
        f4 nc = *(const f4*)(cptr + ln);
        f4 nu = rev ? *(const f4*)(uptr + (L_LEN - 4 - ln)) : *(const f4*)(uptr + ln);

        f4 res;
#pragma unroll
        for (int j = 0; j < 4; ++j) {
            float d = d4[j];
            float uu = rev ? u4[3 - j] : u4[j];
            float e = __expf(d * a);
            h = fmaf(h, e, d * uu * b4[j]);
            float p = h * c4[j];
            // reduce over the 16 state lanes to lane n==15 (DPP row_shr adds)
            p += dpp_sr<0x118>(p);
            p += dpp_sr<0x114>(p);
            p += dpp_sr<0x112>(p);
            p += dpp_sr<0x111>(p);
            res[j] = fmaf(dsc, uu, p); // fold Ds*u into the scan output
        }
        if (n == 15) *(f4*)(yptr + l0) = res;
        d4 = nd; b4 = nb; c4 = nc; u4 = nu;
    }
}

// ---------------- K3: fold (un-scan) + LayerNorm, fused ----------------
// block = one (b, s_out, h); threads (w = tid&31, cg = tid>>5), 12 c's each.
__global__ __launch_bounds__(256) void k3_out(
    const float* __restrict__ yss, const float* __restrict__ nw,
    const float* __restrict__ nb, float* __restrict__ out)
{
    __shared__ float tA[32][97];
    __shared__ float tB[32][97];
    __shared__ float ps[4][8][32];
    __shared__ float stat[4][32];

    int blk = blockIdx.x; // (b*2+so)*32 + h
    int h = blk & 31;
    int bs = blk >> 5;
    int so = bs & 1;
    int b = bs >> 1;
    int w = threadIdx.x & 31;
    int cg = threadIdx.x >> 5;
    int l0 = (h * 32 + w) * 2;
    int l1 = (w * 32 + h) * 2;

    auto Yp = [&](int g, int c) {
        return yss + (((size_t)b * 12 + g) * C_DIM + c) * L_LEN;
    };

    // ---- phase 1: y (out0) and y_dif_extend (out2), stream s1 = so ----
    float sA = 0, qA = 0, sB = 0, qB = 0;
    for (int j = 0; j < 12; ++j) {
        int c = cg * 12 + j;
        f2 f0 = *(const f2*)(Yp(so, c) + l0);
        f2 r0 = *(const f2*)(Yp(6 + so, c) + (2046 - l0));
        f2 f1 = *(const f2*)(Yp(3 + so, c) + l1);
        f2 r1 = *(const f2*)(Yp(9 + so, c) + (2046 - l1));
        float ys0_a = f0.x + r0.y;  // ysf0[l0]   (s2=0)
        float ys0_b = f0.y + r0.x;  // ysf0[l0+1] (s2=1)
        float ys1_a = f1.x + r1.y;
        float ys1_b = f1.y + r1.x;
        float yv = ys0_b + ys1_b; // y   = yd[.., s2=S-1]
        float dv = ys0_a + ys1_a; // ydif = yd[.., s2=0]
        tA[w][c] = yv; tB[w][c] = dv;
        sA += yv; qA += yv * yv; sB += dv; qB += dv * dv;
    }
    ps[0][cg][w] = sA; ps[1][cg][w] = qA; ps[2][cg][w] = sB; ps[3][cg][w] = qB;
    __syncthreads();
    if (threadIdx.x < 32) {
        int ww = threadIdx.x;
        float t0 = 0, t1 = 0, t2 = 0, t3 = 0;
#pragma unroll
        for (int q = 0; q < 8; ++q) {
            t0 += ps[0][q][ww]; t1 += ps[1][q][ww];
            t2 += ps[2][q][ww]; t3 += ps[3][q][ww];
        }
        float muA = t0 * (1.f / 96.f), eqA = t1 * (1.f / 96.f);
        float muB = t2 * (1.f / 96.f), eqB = t3 * (1.f / 96.f);
        stat[0][ww] = muA; stat[1][ww] = rsqrtf(eqA - muA * muA + 1e-5f);
        stat[2][ww] = muB; stat[3][ww] = rsqrtf(eqB - muB * muB + 1e-5f);
    }
    __syncthreads();
    size_t obase = (size_t)blk * 3072;
    for (int e = threadIdx.x; e < 3072; e += 256) {
        int ww = e / 96, c = e % 96;
        float wc = nw[c], bc = nb[c];
        out[obase + e] = (tA[ww][c] - stat[0][ww]) * stat[1][ww] * wc + bc;
        out[2 * 786432 + obase + e] = (tB[ww][c] - stat[2][ww]) * stat[3][ww] * wc + bc;
    }
    __syncthreads();

    // ---- phase 2: y_com (out1), comm stream (g = k*3+2), s2 = so ----
    float sC = 0, qC = 0;
    for (int j = 0; j < 12; ++j) {
        int c = cg * 12 + j;
        f2 f0 = *(const f2*)(Yp(2, c) + l0);
        f2 r0 = *(const f2*)(Yp(8, c) + (2046 - l0));
        f2 f1 = *(const f2*)(Yp(5, c) + l1);
        f2 r1 = *(const f2*)(Yp(11, c) + (2046 - l1));
        float v;
        if (so == 0) v = (f0.x + r0.y) + (f1.x + r1.y);
        else         v = (f0.y + r0.x) + (f1.y + r1.x);
        tA[w][c] = v; sC += v; qC += v * v;
    }
    ps[0][cg][w] = sC; ps[1][cg][w] = qC;
    __syncthreads();
    if (threadIdx.x < 32) {
        int ww = threadIdx.x;
        float t0 = 0, t1 = 0;
#pragma unroll
        for (int q = 0; q < 8; ++q) { t0 += ps[0][q][ww]; t1 += ps[1][q][ww]; }
        float mu = t0 * (1.f / 96.f), eq = t1 * (1.f / 96.f);
        stat[0][ww] = mu; stat[1][ww] = rsqrtf(eq - mu * mu + 1e-5f);
    }
    __syncthreads();
    for (int e = threadIdx.x; e < 3072; e += 256) {
        int ww = e / 96, c = e % 96;
        out[786432 + obase + e] = (tA[ww][c] - stat[0][ww]) * stat[1][ww] * nw[c] + nb[c];
    }
}

extern "C" void kernel_launch(void* const* d_in, const int* in_sizes, int n_in,
                              void* d_out, int out_size, void* d_ws, size_t ws_size,
                              hipStream_t stream)
{
    const float* x = (const float*)d_in[0];
    const float* xpw = (const float*)d_in[1];
    const float* dtw = (const float*)d_in[2];
    const float* dtb = (const float*)d_in[3];
    const float* A_logs = (const float*)d_in[4];
    const float* Ds = (const float*)d_in[5];
    const float* nw = (const float*)d_in[6];
    const float* nb = (const float*)d_in[7];
    float* out = (float*)d_out;

    float* ws = (float*)d_ws;
    float* delta = ws;                 // SZ_DELTA
    float* Bsw = delta + SZ_DELTA;     // SZ_BC
    float* Csw = Bsw + SZ_BC;          // SZ_BC
    float* u6 = Csw + SZ_BC;           // SZ_U6
    float* yss = u6 + SZ_U6;           // SZ_DELTA

    k1_proj<<<dim3(48 * 8), dim3(256), 0, stream>>>(x, xpw, dtw, dtb, delta, Bsw, Csw, u6);
    k2_scan<<<dim3(288), dim3(256), 0, stream>>>(delta, Bsw, Csw, u6, A_logs, Ds, yss);
    k3_out<<<dim3(256), dim3(256), 0, stream>>>(yss, nw, nb, out);
}

// Round 2
// 432.476 us; speedup vs baseline: 1.0109x; 1.0109x over previous
//
#include <hip/hip_runtime.h>
#include <math.h>

typedef float f4 __attribute__((ext_vector_type(4)));
typedef float f2 __attribute__((ext_vector_type(2)));

#define L_LEN 2048
#define C_DIM 96
#define N_DIM 16
#define P_DIM 38
#define R_DIM 6
#define G_DIM 12
#define B_DIM 4
#define NCHUNK 8
#define CLEN 256

// workspace layout (floats)
#define SZ_DELTA (B_DIM * G_DIM * C_DIM * L_LEN) // 9437184
#define SZ_BC (B_DIM * G_DIM * N_DIM * L_LEN)    // 1572864
#define SZ_U6 (B_DIM * 6 * C_DIM * L_LEN)        // 4718592
#define SZ_HCH (B_DIM * G_DIM * C_DIM * N_DIM * NCHUNK) // 589824

// ---------------- K1: cross-scan gather + projections ----------------
__global__ __launch_bounds__(256) void k1_proj(
    const float* __restrict__ x, const float* __restrict__ xpw,
    const float* __restrict__ dtw, const float* __restrict__ dtb,
    float* __restrict__ delta, float* __restrict__ Bsw,
    float* __restrict__ Csw, float* __restrict__ u6)
{
    int blk = blockIdx.x;
    int ltile = blk & 7;
    int bks = blk >> 3;
    int s = bks % 3;
    int k = (bks / 3) & 3;
    int b = bks / 12;
    int g = k * 3 + s;
    int l = ltile * 256 + (int)threadIdx.x;
    int lf = (k < 2) ? l : (L_LEN - 1 - l);
    int s2 = lf & 1;
    int hh, ww;
    if ((k & 1) == 0) { hh = lf >> 6; ww = (lf >> 1) & 31; }
    else              { ww = lf >> 6; hh = (lf >> 1) & 31; }
    int pix = hh * 32 + ww;

    const float* xb = x + (size_t)b * 2 * C_DIM * 1024 + pix;
    const float* wp = xpw + (size_t)g * P_DIM * C_DIM;

    float acc[P_DIM];
#pragma unroll
    for (int p = 0; p < P_DIM; ++p) acc[p] = 0.f;

    for (int c = 0; c < C_DIM; ++c) {
        float x0 = xb[(size_t)c * 1024];
        float x1 = xb[(size_t)(C_DIM + c) * 1024];
        float v;
        if (s == 2)      v = s2 ? x1 : x0;
        else if (s2)     v = s ? x1 : x0;
        else             v = s ? (x1 - x0) : (x0 - x1);
        if (k < 2) u6[(((size_t)b * 6 + g) * C_DIM + c) * L_LEN + l] = v;
#pragma unroll
        for (int p = 0; p < P_DIM; ++p) acc[p] += v * wp[p * C_DIM + c];
    }

    size_t bg = (size_t)b * G_DIM + g;
    const float* wd = dtw + (size_t)g * C_DIM * R_DIM;
    const float* bias = dtb + g * C_DIM;
    for (int c = 0; c < C_DIM; ++c) {
        float dsum = bias[c];
#pragma unroll
        for (int r = 0; r < R_DIM; ++r) dsum += acc[r] * wd[c * R_DIM + r];
        float sp = (dsum > 20.f) ? dsum : log1pf(__expf(dsum));
        delta[(bg * C_DIM + c) * L_LEN + l] = sp;
    }
#pragma unroll
    for (int n = 0; n < N_DIM; ++n) {
        Bsw[(bg * N_DIM + n) * L_LEN + l] = acc[6 + n];
        Csw[(bg * N_DIM + n) * L_LEN + l] = acc[22 + n];
    }
}

// ---------------- K2: chunk-parallel selective scan ----------------
template <int CTRL>
__device__ __forceinline__ float dpp_sr(float v)
{
    int r = __builtin_amdgcn_update_dpp(0, __builtin_bit_cast(int, v), CTRL, 0xF, 0xF, true);
    return __builtin_bit_cast(float, r);
}

// Pass A: local scan per chunk (h0=0). Writes local y (+Ds*u), chunk-end h,
// and chunk propagator prodE = prod(e). block = 16c x 16n; grid 288*8.
__global__ __launch_bounds__(256) void k2_scanA(
    const float* __restrict__ delta, const float* __restrict__ Bsw,
    const float* __restrict__ Csw, const float* __restrict__ u6,
    const float* __restrict__ A_logs, const float* __restrict__ Ds,
    float* __restrict__ yss, float* __restrict__ hend, float* __restrict__ prodE)
{
    int id = blockIdx.x;
    int ch = id & 7;
    int t = id >> 3;
    int cblk = t % 6;
    int bg = t / 6;
    int g = bg % 12;
    int b = bg / 12;
    int n = threadIdx.x & 15;
    int c = cblk * 16 + (threadIdx.x >> 4);

    float a2 = -__expf(A_logs[(g * C_DIM + c) * N_DIM + n]) * 1.44269504f;
    float dsc = Ds[g * C_DIM + c];
    const float* dptr = delta + ((size_t)bg * C_DIM + c) * L_LEN;
    const float* bptr = Bsw + ((size_t)bg * N_DIM + n) * L_LEN;
    const float* cptr = Csw + ((size_t)bg * N_DIM + n) * L_LEN;
    int gu = (g >= 6) ? (g - 6) : g;
    const float* uptr = u6 + (((size_t)b * 6 + gu) * C_DIM + c) * L_LEN;
    const bool rev = (g >= 6);
    float* yptr = yss + ((size_t)bg * C_DIM + c) * L_LEN;

    const int LOFF = ch * CLEN;
    const int LEND = LOFF + CLEN;

    float h = 0.f, P = 1.f;
    f4 d4 = *(const f4*)(dptr + LOFF);
    f4 b4 = *(const f4*)(bptr + LOFF);
    f4 c4 = *(const f4*)(cptr + LOFF);
    f4 u4 = rev ? *(const f4*)(uptr + (L_LEN - 4 - LOFF)) : *(const f4*)(uptr + LOFF);

    for (int l0 = LOFF; l0 < LEND; l0 += 4) {
        int ln = (l0 + 4 < LEND) ? (l0 + 4) : l0;
        f4 nd = *(const f4*)(dptr + ln);
        f4 nb = *(const f4*)(bptr + ln);
        f4 nc = *(const f4*)(cptr + ln);
        f4 nu = rev ? *(const f4*)(uptr + (L_LEN - 4 - ln)) : *(const f4*)(uptr + ln);

        f4 res;
#pragma unroll
        for (int j = 0; j < 4; ++j) {
            float d = d4[j];
            float uu = rev ? u4[3 - j] : u4[j];
            float e = exp2f(d * a2);
            P *= e;
            h = fmaf(h, e, d * uu * b4[j]);
            float p = h * c4[j];
            p += dpp_sr<0x118>(p);
            p += dpp_sr<0x114>(p);
            p += dpp_sr<0x112>(p);
            p += dpp_sr<0x111>(p);
            res[j] = fmaf(dsc, uu, p);
        }
        if (n == 15) *(f4*)(yptr + l0) = res;
        d4 = nd; b4 = nb; c4 = nc; u4 = nu;
    }
    size_t hidx = ((((size_t)bg * C_DIM + c) * N_DIM + n) * NCHUNK) + ch;
    hend[hidx] = h;
    prodE[hidx] = P;
}

// Pass B: compose chunk propagators -> h_start per chunk. 1 thread/(bg,c,n).
__global__ __launch_bounds__(256) void k2_fix(
    const float* __restrict__ hend, const float* __restrict__ prodE,
    float* __restrict__ hstart)
{
    int tid = blockIdx.x * 256 + threadIdx.x; // < 73728
    size_t base = (size_t)tid * NCHUNK;
    float h = 0.f;
#pragma unroll
    for (int ch = 0; ch < NCHUNK; ++ch) {
        hstart[base + ch] = h;
        h = fmaf(h, prodE[base + ch], hend[base + ch]);
    }
}

// Pass C: y(l) += sum_n prefixE_n(l) * h_start_n * C_n(l), chunks 1..7.
__global__ __launch_bounds__(256) void k2_corr(
    const float* __restrict__ delta, const float* __restrict__ Csw,
    const float* __restrict__ A_logs, const float* __restrict__ hstart,
    float* __restrict__ yss)
{
    int id = blockIdx.x;
    int ch = 1 + (id % 7);
    int t = id / 7;
    int cblk = t % 6;
    int bg = t / 6;
    int g = bg % 12;
    int n = threadIdx.x & 15;
    int c = cblk * 16 + (threadIdx.x >> 4);

    float a2 = -__expf(A_logs[(g * C_DIM + c) * N_DIM + n]) * 1.44269504f;
    const float* dptr = delta + ((size_t)bg * C_DIM + c) * L_LEN;
    const float* cptr = Csw + ((size_t)bg * N_DIM + n) * L_LEN;
    float* yptr = yss + ((size_t)bg * C_DIM + c) * L_LEN;
    float h0 = hstart[((((size_t)bg * C_DIM + c) * N_DIM + n) * NCHUNK) + ch];

    const int LOFF = ch * CLEN;
    const int LEND = LOFF + CLEN;

    float P = 1.f;
    f4 d4 = *(const f4*)(dptr + LOFF);
    f4 c4 = *(const f4*)(cptr + LOFF);

    for (int l0 = LOFF; l0 < LEND; l0 += 4) {
        int ln = (l0 + 4 < LEND) ? (l0 + 4) : l0;
        f4 nd = *(const f4*)(dptr + ln);
        f4 nc = *(const f4*)(cptr + ln);
        f4 y4;
        if (n == 15) y4 = *(const f4*)(yptr + l0);

        f4 res;
#pragma unroll
        for (int j = 0; j < 4; ++j) {
            float e = exp2f(d4[j] * a2);
            P *= e;
            float p = (P * h0) * c4[j];
            p += dpp_sr<0x118>(p);
            p += dpp_sr<0x114>(p);
            p += dpp_sr<0x112>(p);
            p += dpp_sr<0x111>(p);
            res[j] = p;
        }
        if (n == 15) {
#pragma unroll
            for (int j = 0; j < 4; ++j) y4[j] += res[j];
            *(f4*)(yptr + l0) = y4;
        }
        d4 = nd; c4 = nc;
    }
}

// ---------------- K3: fold (un-scan) + LayerNorm, fused ----------------
__global__ __launch_bounds__(256) void k3_out(
    const float* __restrict__ yss, const float* __restrict__ nw,
    const float* __restrict__ nb, float* __restrict__ out)
{
    __shared__ float tA[32][97];
    __shared__ float tB[32][97];
    __shared__ float ps[4][8][32];
    __shared__ float stat[4][32];

    int blk = blockIdx.x;
    int h = blk & 31;
    int bs = blk >> 5;
    int so = bs & 1;
    int b = bs >> 1;
    int w = threadIdx.x & 31;
    int cg = threadIdx.x >> 5;
    int l0 = (h * 32 + w) * 2;
    int l1 = (w * 32 + h) * 2;

    auto Yp = [&](int g, int c) {
        return yss + (((size_t)b * 12 + g) * C_DIM + c) * L_LEN;
    };

    float sA = 0, qA = 0, sB = 0, qB = 0;
    for (int j = 0; j < 12; ++j) {
        int c = cg * 12 + j;
        f2 f0 = *(const f2*)(Yp(so, c) + l0);
        f2 r0 = *(const f2*)(Yp(6 + so, c) + (2046 - l0));
        f2 f1 = *(const f2*)(Yp(3 + so, c) + l1);
        f2 r1 = *(const f2*)(Yp(9 + so, c) + (2046 - l1));
        float ys0_a = f0.x + r0.y;
        float ys0_b = f0.y + r0.x;
        float ys1_a = f1.x + r1.y;
        float ys1_b = f1.y + r1.x;
        float yv = ys0_b + ys1_b;
        float dv = ys0_a + ys1_a;
        tA[w][c] = yv; tB[w][c] = dv;
        sA += yv; qA += yv * yv; sB += dv; qB += dv * dv;
    }
    ps[0][cg][w] = sA; ps[1][cg][w] = qA; ps[2][cg][w] = sB; ps[3][cg][w] = qB;
    __syncthreads();
    if (threadIdx.x < 32) {
        int ww = threadIdx.x;
        float t0 = 0, t1 = 0, t2 = 0, t3 = 0;
#pragma unroll
        for (int q = 0; q < 8; ++q) {
            t0 += ps[0][q][ww]; t1 += ps[1][q][ww];
            t2 += ps[2][q][ww]; t3 += ps[3][q][ww];
        }
        float muA = t0 * (1.f / 96.f), eqA = t1 * (1.f / 96.f);
        float muB = t2 * (1.f / 96.f), eqB = t3 * (1.f / 96.f);
        stat[0][ww] = muA; stat[1][ww] = rsqrtf(eqA - muA * muA + 1e-5f);
        stat[2][ww] = muB; stat[3][ww] = rsqrtf(eqB - muB * muB + 1e-5f);
    }
    __syncthreads();
    size_t obase = (size_t)blk * 3072;
    for (int e = threadIdx.x; e < 3072; e += 256) {
        int ww = e / 96, c = e % 96;
        float wc = nw[c], bc = nb[c];
        out[obase + e] = (tA[ww][c] - stat[0][ww]) * stat[1][ww] * wc + bc;
        out[2 * 786432 + obase + e] = (tB[ww][c] - stat[2][ww]) * stat[3][ww] * wc + bc;
    }
    __syncthreads();

    float sC = 0, qC = 0;
    for (int j = 0; j < 12; ++j) {
        int c = cg * 12 + j;
        f2 f0 = *(const f2*)(Yp(2, c) + l0);
        f2 r0 = *(const f2*)(Yp(8, c) + (2046 - l0));
        f2 f1 = *(const f2*)(Yp(5, c) + l1);
        f2 r1 = *(const f2*)(Yp(11, c) + (2046 - l1));
        float v;
        if (so == 0) v = (f0.x + r0.y) + (f1.x + r1.y);
        else         v = (f0.y + r0.x) + (f1.y + r1.x);
        tA[w][c] = v; sC += v; qC += v * v;
    }
    ps[0][cg][w] = sC; ps[1][cg][w] = qC;
    __syncthreads();
    if (threadIdx.x < 32) {
        int ww = threadIdx.x;
        float t0 = 0, t1 = 0;
#pragma unroll
        for (int q = 0; q < 8; ++q) { t0 += ps[0][q][ww]; t1 += ps[1][q][ww]; }
        float mu = t0 * (1.f / 96.f), eq = t1 * (1.f / 96.f);
        stat[0][ww] = mu; stat[1][ww] = rsqrtf(eq - mu * mu + 1e-5f);
    }
    __syncthreads();
    for (int e = threadIdx.x; e < 3072; e += 256) {
        int ww = e / 96, c = e % 96;
        out[786432 + obase + e] = (tA[ww][c] - stat[0][ww]) * stat[1][ww] * nw[c] + nb[c];
    }
}

extern "C" void kernel_launch(void* const* d_in, const int* in_sizes, int n_in,
                              void* d_out, int out_size, void* d_ws, size_t ws_size,
                              hipStream_t stream)
{
    const float* x = (const float*)d_in[0];
    const float* xpw = (const float*)d_in[1];
    const float* dtw = (const float*)d_in[2];
    const float* dtb = (const float*)d_in[3];
    const float* A_logs = (const float*)d_in[4];
    const float* Ds = (const float*)d_in[5];
    const float* nw = (const float*)d_in[6];
    const float* nb = (const float*)d_in[7];
    float* out = (float*)d_out;

    float* ws = (float*)d_ws;
    float* delta = ws;                 // SZ_DELTA
    float* Bsw = delta + SZ_DELTA;     // SZ_BC
    float* Csw = Bsw + SZ_BC;          // SZ_BC
    float* u6 = Csw + SZ_BC;           // SZ_U6
    float* yss = u6 + SZ_U6;           // SZ_DELTA
    float* hend = yss + SZ_DELTA;      // SZ_HCH
    float* prodE = hend + SZ_HCH;      // SZ_HCH
    float* hstart = prodE + SZ_HCH;    // SZ_HCH

    k1_proj<<<dim3(48 * 8), dim3(256), 0, stream>>>(x, xpw, dtw, dtb, delta, Bsw, Csw, u6);
    k2_scanA<<<dim3(288 * NCHUNK), dim3(256), 0, stream>>>(delta, Bsw, Csw, u6, A_logs, Ds,
                                                           yss, hend, prodE);
    k2_fix<<<dim3(288), dim3(256), 0, stream>>>(hend, prodE, hstart);
    k2_corr<<<dim3(288 * (NCHUNK - 1)), dim3(256), 0, stream>>>(delta, Csw, A_logs, hstart, yss);
    k3_out<<<dim3(256), dim3(256), 0, stream>>>(yss, nw, nb, out);
}